// Round 1
// baseline (829.853 us; speedup 1.0000x reference)
//
#include <hip/hip_runtime.h>
#include <math.h>

#define T_IN    480000
#define NFRAMES 1876
#define NF      513      // 1024/2 + 1
#define NFFT    1024
#define HOPSZ   256
#define NBATCH  16

__device__ __forceinline__ int reflect_idx(int q) {
    if (q < 0) q = -q;
    if (q >= T_IN) q = 2 * T_IN - 2 - q;
    return q;
}

// One block (256 threads) = one STFT frame. Computes all 6 channels.
// DIRECT=0: write staged layout ws[(b*T'+t)*6*NF + c*NF + f]  (coalesced in f)
// DIRECT=1: write final layout out[((b*6+c)*NF+f)*T' + t]     (uncoalesced, fallback)
template <int DIRECT>
__global__ __launch_bounds__(256)
void w2t_frame_kernel(const float* __restrict__ x, float* __restrict__ dst) {
    __shared__ float sre[NFFT];
    __shared__ float sim[NFFT];
    __shared__ float smag[NF];
    __shared__ float sdb[NF];
    __shared__ float sdown[657];   // k=2:256 | k=3:171 | k=4:128 | k=5:102

    const int blk = blockIdx.x;
    const int b   = blk / NFRAMES;
    const int t   = blk - b * NFRAMES;
    const int tid = threadIdx.x;

    const float* xl = x + (size_t)(b * 2 + 0) * T_IN;
    const float* xr = x + (size_t)(b * 2 + 1) * T_IN;

    // ---- load + Hann window + bit-reversed scatter (pack stereo as complex) ----
#pragma unroll
    for (int i = 0; i < 4; i++) {
        int n = tid + i * 256;
        int q = reflect_idx(t * HOPSZ + n - NFFT / 2);
        float w = 0.5f - 0.5f * __cosf(6.28318530717958648f * (float)n * (1.0f / 1024.0f));
        int rev = (int)(__brev((unsigned)n) >> 22);   // 10-bit reversal
        sre[rev] = xl[q] * w;
        sim[rev] = xr[q] * w;
    }

    // ---- 1024-pt complex FFT: radix-2 DIT, natural-order output ----
    for (int s = 1; s <= 10; s++) {
        __syncthreads();
        int half = 1 << (s - 1);
#pragma unroll
        for (int it = 0; it < 2; it++) {
            int j  = tid + it * 256;              // 512 butterflies/stage
            int k  = j & (half - 1);
            int g  = j >> (s - 1);
            int i0 = (g << s) + k;
            int i1 = i0 + half;
            float ang = -6.28318530717958648f * (float)k / (float)(1 << s);
            float sn, cs;
            __sincosf(ang, &sn, &cs);
            float ar = sre[i0], ai = sim[i0];
            float br = sre[i1], bi = sim[i1];
            float tr = cs * br - sn * bi;
            float ti = cs * bi + sn * br;
            sre[i0] = ar + tr;  sim[i0] = ai + ti;
            sre[i1] = ar - tr;  sim[i1] = ai - ti;
        }
    }
    __syncthreads();

    const size_t frame_base = (size_t)(b * NFRAMES + t) * 6 * NF;
    auto store = [&](int c, int f, float v) {
        if (DIRECT)
            dst[(((size_t)(b * 6 + c)) * NF + f) * NFRAMES + t] = v;
        else
            dst[frame_base + (size_t)c * NF + f] = v;
    };

    // ---- unpack L/R spectra, per-bin channels ----
    for (int f = tid; f < NF; f += 256) {
        float Ar = sre[f], Ai = sim[f];
        int   mi = (NFFT - f) & (NFFT - 1);
        float Br = sre[mi], Bi = sim[mi];
        // L = (Z(k)+conj(Z(N-k)))/2 ; R = -i(Z(k)-conj(Z(N-k)))/2
        float Lre = 0.5f * (Ar + Br), Lim = 0.5f * (Ai - Bi);
        float Rre = 0.5f * (Ai + Bi), Rim = 0.5f * (Br - Ar);
        float spr = 0.5f * (Lre + Rre), spi = 0.5f * (Lim + Rim);
        float m = sqrtf(spr * spr + spi * spi);
        smag[f] = m;
        sdb[f]  = 20.0f * log10f(m + 1e-10f);
        float ipd = atan2f(Lim, Lre) - atan2f(Rim, Rre);
        float le  = Lre * Lre + Lim * Lim;
        float ren = Rre * Rre + Rim * Rim;
        float pan = (le - ren) / (le + ren + 1e-10f);
        store(0, f, spr);
        store(1, f, spi);
        store(3, f, ipd);
        store(4, f, pan);
    }
    __syncthreads();

    // ---- HPS downsampled arrays (jax.image.resize linear, half-pixel, clamped) ----
    for (int j = tid; j < 657; j += 256) {
        int jj, fd;
        if (j < 256)      { jj = j;       fd = 256; }
        else if (j < 427) { jj = j - 256; fd = 171; }
        else if (j < 555) { jj = j - 427; fd = 128; }
        else              { jj = j - 555; fd = 102; }
        float scale = 513.0f / (float)fd;
        float xc = ((float)jj + 0.5f) * scale - 0.5f;
        float fl = floorf(xc);
        float w  = xc - fl;
        int i0 = (int)fl;
        int c0 = min(max(i0, 0), NF - 1);
        int c1 = min(max(i0 + 1, 0), NF - 1);
        sdown[j] = (1.0f - w) * smag[c0] + w * smag[c1];
    }
    __syncthreads();

    // ---- harmonic product + psychoacoustic spreading ----
    const float SW[21] = {
        7.6945986e-23f, 1.0279774e-18f, 5.0522711e-15f, 9.1347204e-12f,
        6.0758829e-09f, 1.4867195e-06f, 1.3383023e-04f, 4.4318484e-03f,
        5.3990967e-02f, 2.4197072e-01f, 3.9894228e-01f, 2.4197072e-01f,
        5.3990967e-02f, 4.4318484e-03f, 1.3383023e-04f, 1.4867195e-06f,
        6.0758829e-09f, 9.1347204e-12f, 5.0522711e-15f, 1.0279774e-18f,
        7.6945986e-23f };
    const int offs[4] = { 0, 256, 427, 555 };
    const int fds[4]  = { 256, 171, 128, 102 };

    for (int f = tid; f < NF; f += 256) {
        float h = smag[f];
#pragma unroll
        for (int q = 0; q < 4; q++) {
            float scale = (float)fds[q] * (1.0f / 513.0f);
            float xc = ((float)f + 0.5f) * scale - 0.5f;
            float fl = floorf(xc);
            float w  = xc - fl;
            int i0 = (int)fl;
            int c0 = min(max(i0, 0), fds[q] - 1);
            int c1 = min(max(i0 + 1, 0), fds[q] - 1);
            h *= (1.0f - w) * sdown[offs[q] + c0] + w * sdown[offs[q] + c1];
        }
        store(2, f, h);

        float acc = 0.0f;
#pragma unroll
        for (int d = -10; d <= 10; d++) {
            int ff = f + d;
            if (ff >= 0 && ff < NF) acc += SW[d + 10] * sdb[ff];
        }
        store(5, f, acc - 20.0f);
    }
}

// (b,t,c,f) -> (b,c,f,t) tiled transpose
__global__ __launch_bounds__(256)
void w2t_transpose_kernel(const float* __restrict__ ws, float* __restrict__ out) {
    __shared__ float tile[32][33];
    const int bc = blockIdx.z;            // b*6 + c
    const int b  = bc / 6;
    const int c  = bc - b * 6;
    const int f0 = blockIdx.x * 32;
    const int t0 = blockIdx.y * 32;
    const int tx = threadIdx.x;           // 0..31
    const int ty = threadIdx.y;           // 0..7

#pragma unroll
    for (int i = 0; i < 4; i++) {
        int tt = t0 + ty + i * 8;
        int ff = f0 + tx;
        if (tt < NFRAMES && ff < NF)
            tile[ty + i * 8][tx] = ws[((size_t)(b * NFRAMES + tt) * 6 + c) * NF + ff];
    }
    __syncthreads();
#pragma unroll
    for (int i = 0; i < 4; i++) {
        int ff = f0 + ty + i * 8;
        int tt = t0 + tx;
        if (tt < NFRAMES && ff < NF)
            out[((size_t)bc * NF + ff) * NFRAMES + tt] = tile[tx][ty + i * 8];
    }
}

extern "C" void kernel_launch(void* const* d_in, const int* in_sizes, int n_in,
                              void* d_out, int out_size, void* d_ws, size_t ws_size,
                              hipStream_t stream) {
    const float* x = (const float*)d_in[0];
    float* out = (float*)d_out;

    const size_t staged_bytes = (size_t)NBATCH * NFRAMES * 6 * NF * sizeof(float);
    dim3 g1(NBATCH * NFRAMES);

    if (ws_size >= staged_bytes) {
        float* ws = (float*)d_ws;
        hipLaunchKernelGGL((w2t_frame_kernel<0>), g1, dim3(256), 0, stream, x, ws);
        dim3 g2((NF + 31) / 32, (NFRAMES + 31) / 32, NBATCH * 6);
        hipLaunchKernelGGL(w2t_transpose_kernel, g2, dim3(32, 8), 0, stream, ws, out);
    } else {
        hipLaunchKernelGGL((w2t_frame_kernel<1>), g1, dim3(256), 0, stream, x, out);
    }
}

// Round 2
// 715.888 us; speedup vs baseline: 1.1592x; 1.1592x over previous
//
#include <hip/hip_runtime.h>
#include <math.h>

#define T_IN    480000
#define NFRAMES 1876
#define NF      513      // 1024/2 + 1
#define NFFT    1024
#define HOPSZ   256
#define NBATCH  16
#define SSTR    516      // staged f-stride, multiple of 4 so float4 rows stay 16B-aligned

// LDS bank-conflict-avoidance map: +1 float pad every 16
#define MAP(i) ((i) + ((i) >> 4))

__device__ __forceinline__ int reflect_idx(int q) {
    if (q < 0) q = -q;
    if (q >= T_IN) q = 2 * T_IN - 2 - q;
    return q;
}

// base-4 digit reversal of a 10-bit index = 10-bit bit reversal, then swap bit pairs
__device__ __forceinline__ int digitrev4_10(int f) {
    unsigned r = __brev((unsigned)f) >> 22;
    return (int)(((r & 0x155u) << 1) | ((r & 0x2AAu) >> 1));
}

// One block (256 threads) = one STFT frame; computes all 6 channels.
// DIRECT=0: staged layout ws[((b*T'+t)*6+c)*SSTR + f]   (coalesced in f)
// DIRECT=1: final layout  out[((b*6+c)*NF+f)*T' + t]    (uncoalesced fallback)
template <int DIRECT>
__global__ __launch_bounds__(256)
void w2t_frame_kernel(const float* __restrict__ x, float* __restrict__ dst) {
    __shared__ float sre[1088];    // 1024 + pad
    __shared__ float sim[1088];
    __shared__ float twc[512];     // W_1024^j = exp(-2pi i j/1024), j<512
    __shared__ float tws[512];
    __shared__ float smag[NF];
    __shared__ float sdb[NF];
    __shared__ float sdown[657];   // k=2:256 | k=3:171 | k=4:128 | k=5:102

    const int blk = blockIdx.x;
    const int b   = blk / NFRAMES;
    const int t   = blk - b * NFRAMES;
    const int tid = threadIdx.x;

    const float* xl = x + (size_t)(b * 2 + 0) * T_IN;
    const float* xr = x + (size_t)(b * 2 + 1) * T_IN;

    // ---- twiddle table: 2 sincos per thread (vs per-butterfly sincos) ----
    for (int j = tid; j < 512; j += 256) {
        float sn, cs;
        __sincosf(-6.28318530717958648f * (float)j * (1.0f / 1024.0f), &sn, &cs);
        twc[j] = cs; tws[j] = sn;
    }

    // ---- natural-order load + Hann window (stereo packed as complex) ----
#pragma unroll
    for (int i = 0; i < 4; i++) {
        int n = tid + i * 256;
        int q = reflect_idx(t * HOPSZ + n - NFFT / 2);
        float w = 0.5f - 0.5f * __cosf(6.28318530717958648f * (float)n * (1.0f / 1024.0f));
        sre[MAP(n)] = xl[q] * w;
        sim[MAP(n)] = xr[q] * w;
    }

    // ---- 1024-pt complex FFT: radix-4 DIF, in-place, digit-reversed output ----
#pragma unroll
    for (int r = 0; r < 5; r++) {
        __syncthreads();
        const int lq = 8 - 2 * r;        // q = 256,64,16,4,1
        const int q  = 1 << lq;
        int n = tid & (q - 1);
        int g = tid >> lq;
        int base = (g << (lq + 2)) + n;
        int i0 = MAP(base);
        int i1 = MAP(base + q);
        int i2 = MAP(base + 2 * q);
        int i3 = MAP(base + 3 * q);
        float ar = sre[i0], ai = sim[i0];
        float br = sre[i1], bi = sim[i1];
        float cr = sre[i2], ci = sim[i2];
        float dr = sre[i3], di = sim[i3];
        float t0r = ar + cr, t0i = ai + ci;
        float t1r = ar - cr, t1i = ai - ci;
        float t2r = br + dr, t2i = bi + di;
        float t3r = br - dr, t3i = bi - di;
        float u0r = t0r + t2r, u0i = t0i + t2i;
        float v2r = t0r - t2r, v2i = t0i - t2i;
        float v1r = t1r + t3i, v1i = t1i - t3r;   // t1 - i*t3
        float v3r = t1r - t3i, v3i = t1i + t3r;   // t1 + i*t3
        int j1 = n << (2 * r);                    // W_{Nr}^n = W_1024^{n<<2r}
        int j2 = j1 + j1;
        float w1c = twc[j1], w1s = tws[j1];
        float w2c = twc[j2], w2s = tws[j2];
        float w3c = w1c * w2c - w1s * w2s;        // W^{3n} = W^n * W^{2n}
        float w3s = w1c * w2s + w1s * w2c;
        sre[i0] = u0r;                       sim[i0] = u0i;
        sre[i1] = v1r * w1c - v1i * w1s;     sim[i1] = v1r * w1s + v1i * w1c;
        sre[i2] = v2r * w2c - v2i * w2s;     sim[i2] = v2r * w2s + v2i * w2c;
        sre[i3] = v3r * w3c - v3i * w3s;     sim[i3] = v3r * w3s + v3i * w3c;
    }
    __syncthreads();

    const size_t frame_base = (size_t)(b * NFRAMES + t) * 6 * SSTR;
    auto store = [&](int c, int f, float v) {
        if (DIRECT)
            dst[(((size_t)(b * 6 + c)) * NF + f) * NFRAMES + t] = v;
        else
            dst[frame_base + (size_t)c * SSTR + f] = v;
    };

    // ---- unpack L/R spectra (digit-reversed positions), per-bin channels ----
    for (int f = tid; f < NF; f += 256) {
        int pa = MAP(digitrev4_10(f));
        int pb = MAP(digitrev4_10((NFFT - f) & (NFFT - 1)));
        float Ar = sre[pa], Ai = sim[pa];
        float Br = sre[pb], Bi = sim[pb];
        float Lre = 0.5f * (Ar + Br), Lim = 0.5f * (Ai - Bi);
        float Rre = 0.5f * (Ai + Bi), Rim = 0.5f * (Br - Ar);
        float spr = 0.5f * (Lre + Rre), spi = 0.5f * (Lim + Rim);
        float m = sqrtf(spr * spr + spi * spi);
        smag[f] = m;
        sdb[f]  = 20.0f * log10f(m + 1e-10f);
        float ipd = atan2f(Lim, Lre) - atan2f(Rim, Rre);
        float le  = Lre * Lre + Lim * Lim;
        float ren = Rre * Rre + Rim * Rim;
        float pan = (le - ren) / (le + ren + 1e-10f);
        store(0, f, spr);
        store(1, f, spi);
        store(3, f, ipd);
        store(4, f, pan);
    }
    __syncthreads();

    // ---- HPS downsampled arrays (jax.image.resize linear, half-pixel, clamped) ----
    for (int j = tid; j < 657; j += 256) {
        int jj, fd;
        if (j < 256)      { jj = j;       fd = 256; }
        else if (j < 427) { jj = j - 256; fd = 171; }
        else if (j < 555) { jj = j - 427; fd = 128; }
        else              { jj = j - 555; fd = 102; }
        float scale = 513.0f / (float)fd;
        float xc = ((float)jj + 0.5f) * scale - 0.5f;
        float fl = floorf(xc);
        float w  = xc - fl;
        int i0 = (int)fl;
        int c0 = min(max(i0, 0), NF - 1);
        int c1 = min(max(i0 + 1, 0), NF - 1);
        sdown[j] = (1.0f - w) * smag[c0] + w * smag[c1];
    }
    __syncthreads();

    // ---- harmonic product + psychoacoustic spreading ----
    const float SW[21] = {
        7.6945986e-23f, 1.0279774e-18f, 5.0522711e-15f, 9.1347204e-12f,
        6.0758829e-09f, 1.4867195e-06f, 1.3383023e-04f, 4.4318484e-03f,
        5.3990967e-02f, 2.4197072e-01f, 3.9894228e-01f, 2.4197072e-01f,
        5.3990967e-02f, 4.4318484e-03f, 1.3383023e-04f, 1.4867195e-06f,
        6.0758829e-09f, 9.1347204e-12f, 5.0522711e-15f, 1.0279774e-18f,
        7.6945986e-23f };
    const int offs[4] = { 0, 256, 427, 555 };
    const int fds[4]  = { 256, 171, 128, 102 };

    for (int f = tid; f < NF; f += 256) {
        float h = smag[f];
#pragma unroll
        for (int q = 0; q < 4; q++) {
            float scale = (float)fds[q] * (1.0f / 513.0f);
            float xc = ((float)f + 0.5f) * scale - 0.5f;
            float fl = floorf(xc);
            float w  = xc - fl;
            int i0 = (int)fl;
            int c0 = min(max(i0, 0), fds[q] - 1);
            int c1 = min(max(i0 + 1, 0), fds[q] - 1);
            h *= (1.0f - w) * sdown[offs[q] + c0] + w * sdown[offs[q] + c1];
        }
        store(2, f, h);

        float acc = 0.0f;
#pragma unroll
        for (int d = -10; d <= 10; d++) {
            int ff = f + d;
            if (ff >= 0 && ff < NF) acc += SW[d + 10] * sdb[ff];
        }
        store(5, f, acc - 20.0f);
    }
}

// (b,t,c,f) staged -> (b,c,f,t) final; 64x64 tiles, float4 both directions
__global__ __launch_bounds__(256)
void w2t_transpose_kernel(const float* __restrict__ ws, float* __restrict__ out) {
    __shared__ float tile[64][68];     // [f_local][t_local], row stride 68 (16B-aligned, conflict-benign)
    const int bc = blockIdx.z;         // b*6 + c
    const int b  = bc / 6;
    const int c  = bc - b * 6;
    const int f0 = blockIdx.x * 64;
    const int t0 = blockIdx.y * 64;
    const int u   = threadIdx.x;
    const int txq = u & 15;            // quad index
    const int ty  = u >> 4;            // 0..15

    // load: rows = t, float4 along f
#pragma unroll
    for (int i = 0; i < 4; i++) {
        int tl = ty + 16 * i;
        int tt = t0 + tl;
        if (tt < NFRAMES) {
            const float* row = ws + ((size_t)((size_t)b * NFRAMES + tt) * 6 + c) * SSTR + f0;
            int fb = txq * 4;
            if (f0 + fb + 3 < NF) {
                float4 v = *(const float4*)(row + fb);
                tile[fb + 0][tl] = v.x;
                tile[fb + 1][tl] = v.y;
                tile[fb + 2][tl] = v.z;
                tile[fb + 3][tl] = v.w;
            } else {
#pragma unroll
                for (int j = 0; j < 4; j++)
                    if (f0 + fb + j < NF) tile[fb + j][tl] = row[fb + j];
            }
        }
    }
    __syncthreads();

    // store: rows = f, float4 along t
#pragma unroll
    for (int i = 0; i < 4; i++) {
        int fl = ty + 16 * i;
        int ff = f0 + fl;
        if (ff < NF) {
            float* orow = out + ((size_t)bc * NF + ff) * NFRAMES + t0;
            int tb = txq * 4;
            if (t0 + tb + 3 < NFRAMES) {
                float4 v;
                v.x = tile[fl][tb + 0];
                v.y = tile[fl][tb + 1];
                v.z = tile[fl][tb + 2];
                v.w = tile[fl][tb + 3];
                *(float4*)(orow + tb) = v;
            } else {
#pragma unroll
                for (int j = 0; j < 4; j++)
                    if (t0 + tb + j < NFRAMES) orow[tb + j] = tile[fl][tb + j];
            }
        }
    }
}

extern "C" void kernel_launch(void* const* d_in, const int* in_sizes, int n_in,
                              void* d_out, int out_size, void* d_ws, size_t ws_size,
                              hipStream_t stream) {
    const float* x = (const float*)d_in[0];
    float* out = (float*)d_out;

    const size_t staged_bytes = (size_t)NBATCH * NFRAMES * 6 * SSTR * sizeof(float);
    dim3 g1(NBATCH * NFRAMES);

    if (ws_size >= staged_bytes) {
        float* ws = (float*)d_ws;
        hipLaunchKernelGGL((w2t_frame_kernel<0>), g1, dim3(256), 0, stream, x, ws);
        dim3 g2((NF + 63) / 64, (NFRAMES + 63) / 64, NBATCH * 6);
        hipLaunchKernelGGL(w2t_transpose_kernel, g2, dim3(256), 0, stream, ws, out);
    } else {
        hipLaunchKernelGGL((w2t_frame_kernel<1>), g1, dim3(256), 0, stream, x, out);
    }
}